// Round 8
// baseline (138.576 us; speedup 1.0000x reference)
//
#include <hip/hip_runtime.h>
#include <hip/hip_bf16.h>
#include <hip/hip_fp8.h>
#include <stdint.h>
#include <math.h>

#define N_ROWS 8192
#define DIM    512
#define BM     128
#define BK     64
#define NB     (N_ROWS / BM)          // 64 block-rows
#define NTRI   (NB * (NB + 1) / 2)    // 2080 triangle tiles
#define NKT    (DIM / BK)             // 8 K-steps

typedef float f32x4 __attribute__((ext_vector_type(4)));
typedef long  lng2  __attribute__((ext_vector_type(2)));

// f_q row layout (per 64-k block kt, slot u in 0..3, 16B/slot):
//   slot bytes 0..7  = k in [kt*64 + u*8,      +8)
//   slot bytes 8..15 = k in [kt*64 + 32 + u*8, +8)
// so ONE b128 read gives a lane both kk-halves for the 16x16x32 fp8 MFMA pair.

// ---- fused prep: normalize f -> fp8 e4m3 (interleaved layout), posdot, zero S/K ----
__global__ __launch_bounds__(256) void k_prep(const float* __restrict__ feats,
                                              const float* __restrict__ centers,
                                              const int* __restrict__ labels,
                                              unsigned char* __restrict__ f_q,
                                              float* __restrict__ posdot,
                                              float* __restrict__ Ssum,
                                              int* __restrict__ Kcnt) {
    const int row = blockIdx.x;
    const int t = threadIdx.x;
    const float* src = feats + (size_t)row * DIM;
    float v0 = src[t], v1 = src[t + 256];
    float ss = v0 * v0 + v1 * v1;
#pragma unroll
    for (int m = 1; m < 64; m <<= 1) ss += __shfl_xor(ss, m, 64);
    __shared__ float red[12];
    const int lane = t & 63, wid = t >> 6;
    if (lane == 0) red[wid] = ss;
    __syncthreads();
    const float tot = red[0] + red[1] + red[2] + red[3];
    const float scale = 1.0f / fmaxf(sqrtf(tot), 1e-12f);
    const float n0 = v0 * scale, n1 = v1 * scale;
    {
        __hip_fp8_e4m3 q0(n0), q1(n1);
#pragma unroll
        for (int j = 0; j < 2; ++j) {
            const int k  = t + j * 256;
            const int kt = k >> 6, k6 = k & 63;
            const int h  = (k6 >> 5) & 1;
            const int u  = (k6 >> 3) & 3;
            const int pos = kt * 64 + u * 16 + h * 8 + (k6 & 7);
            const unsigned char qb = (j == 0) ? *reinterpret_cast<const unsigned char*>(&q0)
                                              : *reinterpret_cast<const unsigned char*>(&q1);
            f_q[(size_t)row * DIM + pos] = qb;
        }
    }

    const int lab = labels[row];
    const float* c = centers + (size_t)lab * DIM;
    const float c0 = c[t], c1 = c[t + 256];
    float cc = c0 * c0 + c1 * c1;
    float d  = n0 * c0 + n1 * c1;
#pragma unroll
    for (int m = 1; m < 64; m <<= 1) {
        cc += __shfl_xor(cc, m, 64);
        d  += __shfl_xor(d, m, 64);
    }
    if (lane == 0) { red[4 + wid] = cc; red[8 + wid] = d; }
    __syncthreads();
    if (t == 0) {
        const float ctot = red[4] + red[5] + red[6] + red[7];
        const float dtot = red[8] + red[9] + red[10] + red[11];
        posdot[row] = dtot / fmaxf(sqrtf(ctot), 1e-12f);
        Ssum[row] = 0.0f;
        Kcnt[row] = 0;
    }
}

// ---------------- fused triangular A*A^T fp8 GEMM + masked row/col reduction ---
// R5 2-phase dbuf + R6 conflict-free b128 layout, LDS = exactly 32 KB
// (labels/posdot read from global in the epilogue) -> 5 blocks/CU by LDS.
// NO min-waves hint: R7's (256,5) forced VGPR=48 -> acc spills -> 196 MB
// scratch writes. Plain 256 keeps VGPR ~84 (no spill); LDS is the limiter.
__global__ __launch_bounds__(256) void k_pair(const unsigned char* __restrict__ f_q,
                                              const int* __restrict__ labels,
                                              const float* __restrict__ pd,
                                              float* __restrict__ Ssum,
                                              int* __restrict__ Kcnt) {
    __shared__ __align__(16) unsigned char sA[2][BM * BK];
    __shared__ __align__(16) unsigned char sB[2][BM * BK];

    const int tid  = threadIdx.x;
    const int lane = tid & 63;
    const int wid  = tid >> 6;
    const int wr   = wid >> 1, wc = wid & 1;

    // triangle index -> (bi, bj), bi <= bj
    const int t = blockIdx.x;
    int bi = (int)floor((2.0 * NB + 1.0 - sqrt((2.0 * NB + 1.0) * (2.0 * NB + 1.0) - 8.0 * (double)t)) * 0.5);
    while (bi * NB - bi * (bi - 1) / 2 > t) --bi;
    while ((bi + 1) * NB - (bi + 1) * bi / 2 <= t) ++bi;
    const int bj = bi + (t - (bi * NB - bi * (bi - 1) / 2));
    const int rowBase = bi * BM;
    const int colBase = bj * BM;
    const bool offdiag = (bi != bj);

    f32x4 acc[4][4] = {};

    // staging: 8 chunks of 1KB per operand per K-step; 2 chunks/wave/operand.
    // chunk ch covers rows ch*16..+15; lane -> row = ch*16 + (lane>>2),
    // phys slot = lane&3, logical u = (lane&3) ^ ((lane>>3)&3)  (inverse swz).
    const int srow = lane >> 2;
    const int slu  = (lane & 3) ^ ((lane >> 3) & 3);

#define STAGE(KT, P)                                                                       \
    do {                                                                                   \
        const int k0_ = (KT) * BK;                                                         \
        _Pragma("unroll")                                                                  \
        for (int i_ = 0; i_ < 2; ++i_) {                                                   \
            const int ch_ = wid * 2 + i_;                                                  \
            const int r_  = ch_ * 16 + srow;                                               \
            const unsigned char* gA_ = f_q + ((size_t)(rowBase + r_) * DIM + k0_ + slu * 16); \
            const unsigned char* gB_ = f_q + ((size_t)(colBase + r_) * DIM + k0_ + slu * 16); \
            __builtin_amdgcn_global_load_lds(                                              \
                (const __attribute__((address_space(1))) void*)gA_,                        \
                (__attribute__((address_space(3))) void*)(&sA[P][ch_ * 1024]), 16, 0, 0);  \
            __builtin_amdgcn_global_load_lds(                                              \
                (const __attribute__((address_space(1))) void*)gB_,                        \
                (__attribute__((address_space(3))) void*)(&sB[P][ch_ * 1024]), 16, 0, 0);  \
        }                                                                                  \
    } while (0)

    // fragment read geometry: r = (wr|wc)*64 + m*16 + (lane&15), u = lane>>4,
    // phys_u = u ^ ((r>>1)&3) = u ^ ((lane>>1)&3)  (m,wr drop out mod 4)
    const int pu = (lane >> 4) ^ ((lane >> 1) & 3);

#define COMPUTE(P)                                                                         \
    do {                                                                                   \
        lng2 aF[4], bF[4];                                                                 \
        _Pragma("unroll")                                                                  \
        for (int m = 0; m < 4; ++m) {                                                      \
            const int r = wr * 64 + m * 16 + (lane & 15);                                  \
            aF[m] = *(const lng2*)(&sA[P][r * 64 + pu * 16]);                              \
        }                                                                                  \
        _Pragma("unroll")                                                                  \
        for (int n = 0; n < 4; ++n) {                                                      \
            const int r = wc * 64 + n * 16 + (lane & 15);                                  \
            bF[n] = *(const lng2*)(&sB[P][r * 64 + pu * 16]);                              \
        }                                                                                  \
        _Pragma("unroll")                                                                  \
        for (int m = 0; m < 4; ++m)                                                        \
            _Pragma("unroll")                                                              \
            for (int n = 0; n < 4; ++n) {                                                  \
                acc[m][n] = __builtin_amdgcn_mfma_f32_16x16x32_fp8_fp8(aF[m].x, bF[n].x, acc[m][n], 0, 0, 0); \
                acc[m][n] = __builtin_amdgcn_mfma_f32_16x16x32_fp8_fp8(aF[m].y, bF[n].y, acc[m][n], 0, 0, 0); \
            }                                                                              \
    } while (0)

    STAGE(0, 0);
    __syncthreads();   // drains stage(0)

    for (int kt = 0; kt < NKT - 1; ++kt) {
        const int cur = kt & 1;
        STAGE(kt + 1, cur ^ 1);   // prefetch next tile into spare buffer
        COMPUTE(cur);             // MFMA current tile (hides load latency)
        __syncthreads();          // implicit vmcnt(0): prefetch landed; buf cur free
    }
    COMPUTE((NKT - 1) & 1);

#undef STAGE
#undef COMPUTE

    // ---- masked row + column reduction epilogue ----
    // labels/posdot fetched straight from global (32 KB tables, L1/L2-hot,
    // 16-lane broadcast gathers) -- no LDS arrays, keeps LDS at exactly 32 KB.
    // C/D layout: col = lane&15, row = (lane>>4)*4 + g (per 16x16 fragment)
    float colS[4] = {0.f, 0.f, 0.f, 0.f};
    int   colK[4] = {0, 0, 0, 0};
    int   lcv[4]; float pcv[4];
#pragma unroll
    for (int n = 0; n < 4; ++n) {
        const int jl = colBase + wc * 64 + n * 16 + (lane & 15);
        lcv[n] = labels[jl];
        pcv[n] = pd[jl];
    }

#pragma unroll
    for (int m = 0; m < 4; ++m) {
        float rowS[4] = {0.f, 0.f, 0.f, 0.f};
        int   rowK[4] = {0, 0, 0, 0};
        const int rbase = rowBase + wr * 64 + m * 16 + ((lane >> 4) << 2);
        int myLr[4]; float myPd[4];
#pragma unroll
        for (int g = 0; g < 4; ++g) { myLr[g] = labels[rbase + g]; myPd[g] = pd[rbase + g]; }
#pragma unroll
        for (int n = 0; n < 4; ++n) {
#pragma unroll
            for (int g = 0; g < 4; ++g) {
                const float s = acc[m][n][g];
                const bool diff = (myLr[g] != lcv[n]);
                if (diff && s > myPd[g]) { rowS[g] += (s - myPd[g]); rowK[g] += 1; }
                if (offdiag && diff && s > pcv[n]) { colS[n] += (s - pcv[n]); colK[n] += 1; }
            }
        }
#pragma unroll
        for (int g = 0; g < 4; ++g) {
#pragma unroll
            for (int d = 1; d < 16; d <<= 1) {
                rowS[g] += __shfl_xor(rowS[g], d, 64);
                rowK[g] += __shfl_xor(rowK[g], d, 64);
            }
        }
        if ((lane & 15) == 0) {
#pragma unroll
            for (int g = 0; g < 4; ++g) {
                atomicAdd(&Ssum[rbase + g], rowS[g]);
                atomicAdd(&Kcnt[rbase + g], rowK[g]);
            }
        }
    }

    if (offdiag) {
#pragma unroll
        for (int n = 0; n < 4; ++n) {
#pragma unroll
            for (int d = 16; d < 64; d <<= 1) {
                colS[n] += __shfl_xor(colS[n], d, 64);
                colK[n] += __shfl_xor(colK[n], d, 64);
            }
        }
        if (lane < 16) {
#pragma unroll
            for (int n = 0; n < 4; ++n) {
                const int c = colBase + wc * 64 + n * 16 + lane;
                atomicAdd(&Ssum[c], colS[n]);
                atomicAdd(&Kcnt[c], colK[n]);
            }
        }
    }
}

// ---------------- final scalar reduction ----------------
__global__ __launch_bounds__(1024) void k_final(const float* __restrict__ Ssum,
                                                const int* __restrict__ Kcnt,
                                                float* __restrict__ out) {
    const int t = threadIdx.x;
    double sum = 0.0; int cnt = 0;
    for (int i = t; i < N_ROWS; i += 1024) {
        const int k = Kcnt[i];
        if (k > 0) { sum += (double)Ssum[i] / (double)k; cnt += 1; }
    }
#pragma unroll
    for (int d = 1; d < 64; d <<= 1) {
        sum += __shfl_xor(sum, d, 64);
        cnt += __shfl_xor(cnt, d, 64);
    }
    __shared__ double s_sum[16];
    __shared__ int    s_cnt[16];
    const int lane = t & 63, wid = t >> 6;
    if (lane == 0) { s_sum[wid] = sum; s_cnt[wid] = cnt; }
    __syncthreads();
    if (t == 0) {
        double ts = 0.0; int tc = 0;
#pragma unroll
        for (int w = 0; w < 16; ++w) { ts += s_sum[w]; tc += s_cnt[w]; }
        out[0] = (float)(tc > 0 ? ts / (double)tc : ts);
    }
}

extern "C" void kernel_launch(void* const* d_in, const int* in_sizes, int n_in,
                              void* d_out, int out_size, void* d_ws, size_t ws_size,
                              hipStream_t stream) {
    const float* features = (const float*)d_in[0];
    const float* centers  = (const float*)d_in[1];
    const int*   labels   = (const int*)d_in[2];
    float* out = (float*)d_out;

    char* ws = (char*)d_ws;
    unsigned char* f_q    = (unsigned char*)(ws);                 // 4,194,304 B
    float*         posdot = (float*)(ws + 0x400000);              // 32,768 B
    float*         Ssum   = (float*)(ws + 0x400000 + 0x8000);
    int*           Kcnt   = (int*)  (ws + 0x400000 + 0x10000);

    k_prep<<<N_ROWS, 256, 0, stream>>>(features, centers, labels, f_q, posdot, Ssum, Kcnt);
    k_pair<<<NTRI, 256, 0, stream>>>(f_q, labels, posdot, Ssum, Kcnt);
    k_final<<<1, 1024, 0, stream>>>(Ssum, Kcnt, out);
}

// Round 9
// 92.191 us; speedup vs baseline: 1.5031x; 1.5031x over previous
//
#include <hip/hip_runtime.h>
#include <hip/hip_bf16.h>
#include <hip/hip_fp8.h>
#include <stdint.h>
#include <math.h>

#define N_ROWS 8192
#define DIM    512
#define BM     128
#define BK     64
#define NB     (N_ROWS / BM)          // 64 block-rows
#define NTRI   (NB * (NB + 1) / 2)    // 2080 triangle tiles
#define NKT    (DIM / BK)             // 8 K-steps

typedef float f32x4 __attribute__((ext_vector_type(4)));
typedef long  lng2  __attribute__((ext_vector_type(2)));

// f_q row layout (per 64-k block kt, slot u in 0..3, 16B/slot):
//   slot bytes 0..7  = k in [kt*64 + u*8,      +8)
//   slot bytes 8..15 = k in [kt*64 + 32 + u*8, +8)
// so ONE b128 read gives a lane both kk-halves for the 16x16x32 fp8 MFMA pair.

// ---- fused prep: normalize f -> fp8 e4m3 (interleaved layout), posdot, zero S/K ----
__global__ __launch_bounds__(256) void k_prep(const float* __restrict__ feats,
                                              const float* __restrict__ centers,
                                              const int* __restrict__ labels,
                                              unsigned char* __restrict__ f_q,
                                              float* __restrict__ posdot,
                                              float* __restrict__ Ssum,
                                              int* __restrict__ Kcnt) {
    const int row = blockIdx.x;
    const int t = threadIdx.x;
    const float* src = feats + (size_t)row * DIM;
    float v0 = src[t], v1 = src[t + 256];
    float ss = v0 * v0 + v1 * v1;
#pragma unroll
    for (int m = 1; m < 64; m <<= 1) ss += __shfl_xor(ss, m, 64);
    __shared__ float red[12];
    const int lane = t & 63, wid = t >> 6;
    if (lane == 0) red[wid] = ss;
    __syncthreads();
    const float tot = red[0] + red[1] + red[2] + red[3];
    const float scale = 1.0f / fmaxf(sqrtf(tot), 1e-12f);
    const float n0 = v0 * scale, n1 = v1 * scale;
    {
        __hip_fp8_e4m3 q0(n0), q1(n1);
#pragma unroll
        for (int j = 0; j < 2; ++j) {
            const int k  = t + j * 256;
            const int kt = k >> 6, k6 = k & 63;
            const int h  = (k6 >> 5) & 1;
            const int u  = (k6 >> 3) & 3;
            const int pos = kt * 64 + u * 16 + h * 8 + (k6 & 7);
            const unsigned char qb = (j == 0) ? *reinterpret_cast<const unsigned char*>(&q0)
                                              : *reinterpret_cast<const unsigned char*>(&q1);
            f_q[(size_t)row * DIM + pos] = qb;
        }
    }

    const int lab = labels[row];
    const float* c = centers + (size_t)lab * DIM;
    const float c0 = c[t], c1 = c[t + 256];
    float cc = c0 * c0 + c1 * c1;
    float d  = n0 * c0 + n1 * c1;
#pragma unroll
    for (int m = 1; m < 64; m <<= 1) {
        cc += __shfl_xor(cc, m, 64);
        d  += __shfl_xor(d, m, 64);
    }
    if (lane == 0) { red[4 + wid] = cc; red[8 + wid] = d; }
    __syncthreads();
    if (t == 0) {
        const float ctot = red[4] + red[5] + red[6] + red[7];
        const float dtot = red[8] + red[9] + red[10] + red[11];
        posdot[row] = dtot / fmaxf(sqrtf(ctot), 1e-12f);
        Ssum[row] = 0.0f;
        Kcnt[row] = 0;
    }
}

// ---------------- fused triangular A*A^T fp8 GEMM + masked row/col reduction ---
// R5 + R6 union: 2-buffer 2-phase dbuf (4 blocks/CU at 34.8 KB LDS, VGPR ~84)
// + conflict-free b128 pair-interleaved fragment reads (R6 layout).
// LDS swizzle: phys_u = u ^ ((lane>>1)&3) at 16B slots; one ds_read_b128
// per fragment feeds both kk-halves of the MFMA pair.
__global__ __launch_bounds__(256) void k_pair(const unsigned char* __restrict__ f_q,
                                              const int* __restrict__ labels,
                                              const float* __restrict__ pd,
                                              float* __restrict__ Ssum,
                                              int* __restrict__ Kcnt) {
    __shared__ __align__(16) unsigned char sA[2][BM * BK];
    __shared__ __align__(16) unsigned char sB[2][BM * BK];
    __shared__ int   s_lr[BM];
    __shared__ int   s_lc[BM];
    __shared__ float s_pd[BM];
    __shared__ float s_pc[BM];

    const int tid  = threadIdx.x;
    const int lane = tid & 63;
    const int wid  = tid >> 6;
    const int wr   = wid >> 1, wc = wid & 1;

    // triangle index -> (bi, bj), bi <= bj
    const int t = blockIdx.x;
    int bi = (int)floor((2.0 * NB + 1.0 - sqrt((2.0 * NB + 1.0) * (2.0 * NB + 1.0) - 8.0 * (double)t)) * 0.5);
    while (bi * NB - bi * (bi - 1) / 2 > t) --bi;
    while ((bi + 1) * NB - (bi + 1) * bi / 2 <= t) ++bi;
    const int bj = bi + (t - (bi * NB - bi * (bi - 1) / 2));
    const int rowBase = bi * BM;
    const int colBase = bj * BM;
    const bool offdiag = (bi != bj);

    if (tid < BM) {
        s_lr[tid] = labels[rowBase + tid];
        s_pd[tid] = pd[rowBase + tid];
    } else {
        s_lc[tid - BM] = labels[colBase + tid - BM];
        s_pc[tid - BM] = pd[colBase + tid - BM];
    }

    f32x4 acc[4][4] = {};

    // staging: 8 chunks of 1KB per operand per K-step; 2 chunks/wave/operand.
    // chunk ch covers rows ch*16..+15; lane -> row = ch*16 + (lane>>2),
    // phys slot = lane&3, logical u = (lane&3) ^ ((lane>>3)&3)  (inverse swz).
    const int srow = lane >> 2;
    const int slu  = (lane & 3) ^ ((lane >> 3) & 3);

#define STAGE(KT, P)                                                                       \
    do {                                                                                   \
        const int k0_ = (KT) * BK;                                                         \
        _Pragma("unroll")                                                                  \
        for (int i_ = 0; i_ < 2; ++i_) {                                                   \
            const int ch_ = wid * 2 + i_;                                                  \
            const int r_  = ch_ * 16 + srow;                                               \
            const unsigned char* gA_ = f_q + ((size_t)(rowBase + r_) * DIM + k0_ + slu * 16); \
            const unsigned char* gB_ = f_q + ((size_t)(colBase + r_) * DIM + k0_ + slu * 16); \
            __builtin_amdgcn_global_load_lds(                                              \
                (const __attribute__((address_space(1))) void*)gA_,                        \
                (__attribute__((address_space(3))) void*)(&sA[P][ch_ * 1024]), 16, 0, 0);  \
            __builtin_amdgcn_global_load_lds(                                              \
                (const __attribute__((address_space(1))) void*)gB_,                        \
                (__attribute__((address_space(3))) void*)(&sB[P][ch_ * 1024]), 16, 0, 0);  \
        }                                                                                  \
    } while (0)

    // fragment read geometry: r = (wr|wc)*64 + m*16 + (lane&15), u = lane>>4,
    // phys_u = u ^ ((r>>1)&3) = u ^ ((lane>>1)&3)  (m,wr drop out mod 4)
    const int pu = (lane >> 4) ^ ((lane >> 1) & 3);

#define COMPUTE(P)                                                                         \
    do {                                                                                   \
        lng2 aF[4], bF[4];                                                                 \
        _Pragma("unroll")                                                                  \
        for (int m = 0; m < 4; ++m) {                                                      \
            const int r = wr * 64 + m * 16 + (lane & 15);                                  \
            aF[m] = *(const lng2*)(&sA[P][r * 64 + pu * 16]);                              \
        }                                                                                  \
        _Pragma("unroll")                                                                  \
        for (int n = 0; n < 4; ++n) {                                                      \
            const int r = wc * 64 + n * 16 + (lane & 15);                                  \
            bF[n] = *(const lng2*)(&sB[P][r * 64 + pu * 16]);                              \
        }                                                                                  \
        _Pragma("unroll")                                                                  \
        for (int m = 0; m < 4; ++m)                                                        \
            _Pragma("unroll")                                                              \
            for (int n = 0; n < 4; ++n) {                                                  \
                acc[m][n] = __builtin_amdgcn_mfma_f32_16x16x32_fp8_fp8(aF[m].x, bF[n].x, acc[m][n], 0, 0, 0); \
                acc[m][n] = __builtin_amdgcn_mfma_f32_16x16x32_fp8_fp8(aF[m].y, bF[n].y, acc[m][n], 0, 0, 0); \
            }                                                                              \
    } while (0)

    STAGE(0, 0);
    __syncthreads();   // drains stage(0) + publishes s_lr/s_pd/s_lc/s_pc

    for (int kt = 0; kt < NKT - 1; ++kt) {
        const int cur = kt & 1;
        STAGE(kt + 1, cur ^ 1);   // prefetch next tile into spare buffer
        COMPUTE(cur);             // MFMA current tile (hides load latency)
        __syncthreads();          // implicit vmcnt(0): prefetch landed; buf cur free
    }
    COMPUTE((NKT - 1) & 1);

#undef STAGE
#undef COMPUTE

    // ---- masked row + column reduction epilogue ----
    // C/D layout: col = lane&15, row = (lane>>4)*4 + g (per 16x16 fragment)
    float colS[4] = {0.f, 0.f, 0.f, 0.f};
    int   colK[4] = {0, 0, 0, 0};
    int   lcv[4]; float pcv[4];
#pragma unroll
    for (int n = 0; n < 4; ++n) {
        const int jl = wc * 64 + n * 16 + (lane & 15);
        lcv[n] = s_lc[jl];
        pcv[n] = s_pc[jl];
    }

#pragma unroll
    for (int m = 0; m < 4; ++m) {
        float rowS[4] = {0.f, 0.f, 0.f, 0.f};
        int   rowK[4] = {0, 0, 0, 0};
        const int rbase = wr * 64 + m * 16 + ((lane >> 4) << 2);
        int myLr[4]; float myPd[4];
#pragma unroll
        for (int g = 0; g < 4; ++g) { myLr[g] = s_lr[rbase + g]; myPd[g] = s_pd[rbase + g]; }
#pragma unroll
        for (int n = 0; n < 4; ++n) {
#pragma unroll
            for (int g = 0; g < 4; ++g) {
                const float s = acc[m][n][g];
                const bool diff = (myLr[g] != lcv[n]);
                if (diff && s > myPd[g]) { rowS[g] += (s - myPd[g]); rowK[g] += 1; }
                if (offdiag && diff && s > pcv[n]) { colS[n] += (s - pcv[n]); colK[n] += 1; }
            }
        }
#pragma unroll
        for (int g = 0; g < 4; ++g) {
#pragma unroll
            for (int d = 1; d < 16; d <<= 1) {
                rowS[g] += __shfl_xor(rowS[g], d, 64);
                rowK[g] += __shfl_xor(rowK[g], d, 64);
            }
        }
        if ((lane & 15) == 0) {
#pragma unroll
            for (int g = 0; g < 4; ++g) {
                const int r = rowBase + rbase + g;
                atomicAdd(&Ssum[r], rowS[g]);
                atomicAdd(&Kcnt[r], rowK[g]);
            }
        }
    }

    if (offdiag) {
#pragma unroll
        for (int n = 0; n < 4; ++n) {
#pragma unroll
            for (int d = 16; d < 64; d <<= 1) {
                colS[n] += __shfl_xor(colS[n], d, 64);
                colK[n] += __shfl_xor(colK[n], d, 64);
            }
        }
        if (lane < 16) {
#pragma unroll
            for (int n = 0; n < 4; ++n) {
                const int c = colBase + wc * 64 + n * 16 + lane;
                atomicAdd(&Ssum[c], colS[n]);
                atomicAdd(&Kcnt[c], colK[n]);
            }
        }
    }
}

// ---------------- final scalar reduction ----------------
__global__ __launch_bounds__(1024) void k_final(const float* __restrict__ Ssum,
                                                const int* __restrict__ Kcnt,
                                                float* __restrict__ out) {
    const int t = threadIdx.x;
    double sum = 0.0; int cnt = 0;
    for (int i = t; i < N_ROWS; i += 1024) {
        const int k = Kcnt[i];
        if (k > 0) { sum += (double)Ssum[i] / (double)k; cnt += 1; }
    }
#pragma unroll
    for (int d = 1; d < 64; d <<= 1) {
        sum += __shfl_xor(sum, d, 64);
        cnt += __shfl_xor(cnt, d, 64);
    }
    __shared__ double s_sum[16];
    __shared__ int    s_cnt[16];
    const int lane = t & 63, wid = t >> 6;
    if (lane == 0) { s_sum[wid] = sum; s_cnt[wid] = cnt; }
    __syncthreads();
    if (t == 0) {
        double ts = 0.0; int tc = 0;
#pragma unroll
        for (int w = 0; w < 16; ++w) { ts += s_sum[w]; tc += s_cnt[w]; }
        out[0] = (float)(tc > 0 ? ts / (double)tc : ts);
    }
}

extern "C" void kernel_launch(void* const* d_in, const int* in_sizes, int n_in,
                              void* d_out, int out_size, void* d_ws, size_t ws_size,
                              hipStream_t stream) {
    const float* features = (const float*)d_in[0];
    const float* centers  = (const float*)d_in[1];
    const int*   labels   = (const int*)d_in[2];
    float* out = (float*)d_out;

    char* ws = (char*)d_ws;
    unsigned char* f_q    = (unsigned char*)(ws);                 // 4,194,304 B
    float*         posdot = (float*)(ws + 0x400000);              // 32,768 B
    float*         Ssum   = (float*)(ws + 0x400000 + 0x8000);
    int*           Kcnt   = (int*)  (ws + 0x400000 + 0x10000);

    k_prep<<<N_ROWS, 256, 0, stream>>>(features, centers, labels, f_q, posdot, Ssum, Kcnt);
    k_pair<<<NTRI, 256, 0, stream>>>(f_q, labels, posdot, Ssum, Kcnt);
    k_final<<<1, 1024, 0, stream>>>(Ssum, Kcnt, out);
}